// Round 1
// baseline (275.590 us; speedup 1.0000x reference)
//
#include <hip/hip_runtime.h>
#include <math.h>

// Problem constants (fixed by the reference)
#define Bn   32
#define Cn   256
#define Kn   3
#define HWn  4096      // 64*64
#define HW4n 1024      // HW in float4 units
#define BN_EPS 1e-5f

// ---------------------------------------------------------------------------
// Kernel 1: global average pool. One block per (b,c); 256 threads each read
// 4 float4 (16 floats) -> block reduce -> gap[b*C+c].
// ---------------------------------------------------------------------------
__global__ __launch_bounds__(256) void gap_kernel(const float* __restrict__ x,
                                                  float* __restrict__ gap) {
    const int bc = blockIdx.x;                     // b*Cn + c
    const float4* px = (const float4*)(x + (size_t)bc * HWn);
    const int t = threadIdx.x;
    float s = 0.f;
#pragma unroll
    for (int i = 0; i < 4; ++i) {
        float4 v = px[t + i * 256];
        s += (v.x + v.y) + (v.z + v.w);
    }
    // wave64 shuffle reduce
#pragma unroll
    for (int off = 32; off > 0; off >>= 1) s += __shfl_down(s, off, 64);
    __shared__ float ls[4];
    const int wave = t >> 6, lane = t & 63;
    if (lane == 0) ls[wave] = s;
    __syncthreads();
    if (t == 0) {
        gap[bc] = (ls[0] + ls[1] + ls[2] + ls[3]) * (1.0f / (float)HWn);
    }
}

// ---------------------------------------------------------------------------
// Kernel 2: f[b,o] = dot(gap[b,:], conv_w[o,:]) -> BN(eval) -> sigmoid,
// then fold gamma/beta into per-(k,b,c) stencil coefficients:
//   a0 = s0*gamma[c]; a1 = s1*gamma[c] + beta[c]; a2 = s2*gamma[c]
// A layout: [K][B][C]. 24576 threads total (= 96 blocks * 256).
// ---------------------------------------------------------------------------
__global__ __launch_bounds__(256) void filt_kernel(
        const float* __restrict__ gap, const float* __restrict__ conv_w,
        const float* __restrict__ bn_w, const float* __restrict__ bn_b,
        const float* __restrict__ bn_mean, const float* __restrict__ bn_var,
        const float* __restrict__ gamma, const float* __restrict__ beta,
        float* __restrict__ A) {
    const int gid = blockIdx.x * 256 + threadIdx.x;   // 0 .. B*K*C-1
    const int b = gid / (Kn * Cn);
    const int o = gid % (Kn * Cn);
    const float4* g4 = (const float4*)(gap + b * Cn);
    const float4* w4 = (const float4*)(conv_w + (size_t)o * Cn);
    float acc = 0.f;
#pragma unroll 8
    for (int i = 0; i < Cn / 4; ++i) {
        float4 g = g4[i], w = w4[i];
        acc += g.x * w.x + g.y * w.y + g.z * w.z + g.w * w.w;
    }
    float fv = (acc - bn_mean[o]) * rsqrtf(bn_var[o] + BN_EPS) * bn_w[o] + bn_b[o];
    float s = 1.0f / (1.0f + expf(-fv));
    const int k = o / Cn, c = o % Cn;
    float a = (k == 1) ? (s * gamma[c] + beta[c]) : (s * gamma[c]);
    A[(size_t)k * (Bn * Cn) + b * Cn + c] = a;
}

// ---------------------------------------------------------------------------
// Kernel 3: 3-tap channel stencil with rolling register window.
// Thread mapping: gid over [B][8 strips][1024 hw4]; each thread walks 32
// channels at one float4 (h,w) position. Each x element loaded once per
// strip (+2 boundary channels). Coefficients staged in LDS (wave-uniform
// broadcast reads -> conflict-free).
// Reflect edges: c==0 uses xm=x[1]; c==C-1 uses xn=x[C-2].
// ---------------------------------------------------------------------------
__global__ __launch_bounds__(256) void stencil_kernel(const float* __restrict__ x,
                                                      const float* __restrict__ A,
                                                      float* __restrict__ out) {
    const int gid  = blockIdx.x * 256 + threadIdx.x;
    const int hw4  = gid & (HW4n - 1);
    const int strip = (gid >> 10) & 7;
    const int b    = gid >> 13;
    const int c0   = strip * 32;

    __shared__ float a0s[32], a1s[32], a2s[32];
    const int t = threadIdx.x;
    if (t < 96) {
        const int k = t >> 5, cc = t & 31;
        float v = A[(size_t)k * (Bn * Cn) + b * Cn + c0 + cc];
        if (k == 0) a0s[cc] = v;
        else if (k == 1) a1s[cc] = v;
        else a2s[cc] = v;
    }
    __syncthreads();

    const float4* px  = (const float4*)x;
    float4* pout      = (float4*)out;
    const size_t base = (size_t)b * Cn * HW4n + hw4;   // float4 units

    const int cm = (c0 == 0) ? 1 : c0 - 1;             // reflect at c=0
    float4 xm = px[base + (size_t)cm * HW4n];
    float4 xc = px[base + (size_t)c0 * HW4n];

#pragma unroll 4
    for (int i = 0; i < 32; ++i) {
        const int c  = c0 + i;
        const int cn = (c == Cn - 1) ? (Cn - 2) : (c + 1);   // reflect at c=C-1
        float4 xn = px[base + (size_t)cn * HW4n];
        const float a0 = a0s[i], a1 = a1s[i], a2 = a2s[i];
        float4 o;
        o.x = fmaf(a0, xm.x, fmaf(a1, xc.x, a2 * xn.x));
        o.y = fmaf(a0, xm.y, fmaf(a1, xc.y, a2 * xn.y));
        o.z = fmaf(a0, xm.z, fmaf(a1, xc.z, a2 * xn.z));
        o.w = fmaf(a0, xm.w, fmaf(a1, xc.w, a2 * xn.w));
        pout[base + (size_t)c * HW4n] = o;
        xm = xc;
        xc = xn;
    }
}

extern "C" void kernel_launch(void* const* d_in, const int* in_sizes, int n_in,
                              void* d_out, int out_size, void* d_ws, size_t ws_size,
                              hipStream_t stream) {
    const float* x       = (const float*)d_in[0];
    const float* conv_w  = (const float*)d_in[1];
    const float* bn_w    = (const float*)d_in[2];
    const float* bn_b    = (const float*)d_in[3];
    const float* bn_mean = (const float*)d_in[4];
    const float* bn_var  = (const float*)d_in[5];
    const float* gamma   = (const float*)d_in[6];
    const float* beta    = (const float*)d_in[7];
    float* out = (float*)d_out;

    float* gap = (float*)d_ws;            // [B*C]           = 32 KiB
    float* A   = gap + Bn * Cn;           // [K][B][C]       = 96 KiB

    gap_kernel<<<Bn * Cn, 256, 0, stream>>>(x, gap);
    filt_kernel<<<(Bn * Kn * Cn) / 256, 256, 0, stream>>>(
        gap, conv_w, bn_w, bn_b, bn_mean, bn_var, gamma, beta, A);
    stencil_kernel<<<(Bn * 8 * HW4n) / 256, 256, 0, stream>>>(x, A, out);
}

// Round 2
// 274.140 us; speedup vs baseline: 1.0053x; 1.0053x over previous
//
#include <hip/hip_runtime.h>
#include <math.h>

// Problem constants (fixed by the reference)
#define Bn   32
#define Cn   256
#define Kn   3
#define HWn  4096      // 64*64
#define HW4n 1024      // HW in float4 units
#define BN_EPS 1e-5f
#define SPC  16        // channels per strip (stencil)
#define NSTRIP (Cn / SPC)

typedef float f4 __attribute__((ext_vector_type(4)));

// ---------------------------------------------------------------------------
// Kernel 1: global average pool. One block per (b,c); 256 threads each read
// 4 float4 (16 floats) -> block reduce -> gap[b*C+c].
// Normal (caching) loads on purpose: this pass warms x into Infinity Cache
// for the stencil pass.
// ---------------------------------------------------------------------------
__global__ __launch_bounds__(256) void gap_kernel(const float* __restrict__ x,
                                                  float* __restrict__ gap) {
    const int bc = blockIdx.x;                     // b*Cn + c
    const f4* px = (const f4*)(x + (size_t)bc * HWn);
    const int t = threadIdx.x;
    float s = 0.f;
#pragma unroll
    for (int i = 0; i < 4; ++i) {
        f4 v = px[t + i * 256];
        s += (v.x + v.y) + (v.z + v.w);
    }
    // wave64 shuffle reduce
#pragma unroll
    for (int off = 32; off > 0; off >>= 1) s += __shfl_down(s, off, 64);
    __shared__ float ls[4];
    const int wave = t >> 6, lane = t & 63;
    if (lane == 0) ls[wave] = s;
    __syncthreads();
    if (t == 0) {
        gap[bc] = (ls[0] + ls[1] + ls[2] + ls[3]) * (1.0f / (float)HWn);
    }
}

// ---------------------------------------------------------------------------
// Kernel 2: f[b,o] = dot(gap[b,:], conv_w[o,:]) -> BN(eval) -> sigmoid,
// then fold gamma/beta into per-(k,b,c) stencil coefficients:
//   a0 = s0*gamma[c]; a1 = s1*gamma[c] + beta[c]; a2 = s2*gamma[c]
// A layout: [K][B][C].
// ---------------------------------------------------------------------------
__global__ __launch_bounds__(256) void filt_kernel(
        const float* __restrict__ gap, const float* __restrict__ conv_w,
        const float* __restrict__ bn_w, const float* __restrict__ bn_b,
        const float* __restrict__ bn_mean, const float* __restrict__ bn_var,
        const float* __restrict__ gamma, const float* __restrict__ beta,
        float* __restrict__ A) {
    const int gid = blockIdx.x * 256 + threadIdx.x;   // 0 .. B*K*C-1
    const int b = gid / (Kn * Cn);
    const int o = gid % (Kn * Cn);
    const f4* g4 = (const f4*)(gap + b * Cn);
    const f4* w4 = (const f4*)(conv_w + (size_t)o * Cn);
    float acc = 0.f;
#pragma unroll 8
    for (int i = 0; i < Cn / 4; ++i) {
        f4 g = g4[i], w = w4[i];
        acc += g.x * w.x + g.y * w.y + g.z * w.z + g.w * w.w;
    }
    float fv = (acc - bn_mean[o]) * rsqrtf(bn_var[o] + BN_EPS) * bn_w[o] + bn_b[o];
    float s = 1.0f / (1.0f + expf(-fv));
    const int k = o / Cn, c = o % Cn;
    float a = (k == 1) ? (s * gamma[c] + beta[c]) : (s * gamma[c]);
    A[(size_t)k * (Bn * Cn) + b * Cn + c] = a;
}

// ---------------------------------------------------------------------------
// Kernel 3: 3-tap channel stencil, rolling register window over SPC=16
// channels per thread. 2048 blocks -> 8 blocks/CU -> 32 waves/CU (max occ).
// x reads are single-use here -> non-temporal loads; out writes are
// write-once -> non-temporal stores, so out does NOT evict x from the 256 MiB
// Infinity Cache mid-pass (x is exactly half of L3).
// Reflect edges: c==0 uses x[1]; c==C-1 uses x[C-2].
// ---------------------------------------------------------------------------
__global__ __launch_bounds__(256) void stencil_kernel(const float* __restrict__ x,
                                                      const float* __restrict__ A,
                                                      float* __restrict__ out) {
    const int gid   = blockIdx.x * 256 + threadIdx.x;
    const int hw4   = gid & (HW4n - 1);
    const int strip = (gid >> 10) & (NSTRIP - 1);
    const int b     = gid >> 14;
    const int c0    = strip * SPC;

    __shared__ float a0s[SPC], a1s[SPC], a2s[SPC];
    const int t = threadIdx.x;
    if (t < 3 * SPC) {
        const int k = t / SPC, cc = t % SPC;
        float v = A[(size_t)k * (Bn * Cn) + b * Cn + c0 + cc];
        if (k == 0) a0s[cc] = v;
        else if (k == 1) a1s[cc] = v;
        else a2s[cc] = v;
    }
    __syncthreads();

    const f4* px  = (const f4*)x;
    f4* pout      = (f4*)out;
    const size_t base = (size_t)b * Cn * HW4n + hw4;   // float4 units

    const int cm = (c0 == 0) ? 1 : c0 - 1;             // reflect at c=0
    f4 xm = __builtin_nontemporal_load(&px[base + (size_t)cm * HW4n]);
    f4 xc = __builtin_nontemporal_load(&px[base + (size_t)c0 * HW4n]);

#pragma unroll 4
    for (int i = 0; i < SPC; ++i) {
        const int c  = c0 + i;
        const int cn = (c == Cn - 1) ? (Cn - 2) : (c + 1);   // reflect at c=C-1
        f4 xn = __builtin_nontemporal_load(&px[base + (size_t)cn * HW4n]);
        const float a0 = a0s[i], a1 = a1s[i], a2 = a2s[i];
        f4 o;
        o.x = fmaf(a0, xm.x, fmaf(a1, xc.x, a2 * xn.x));
        o.y = fmaf(a0, xm.y, fmaf(a1, xc.y, a2 * xn.y));
        o.z = fmaf(a0, xm.z, fmaf(a1, xc.z, a2 * xn.z));
        o.w = fmaf(a0, xm.w, fmaf(a1, xc.w, a2 * xn.w));
        __builtin_nontemporal_store(o, &pout[base + (size_t)c * HW4n]);
        xm = xc;
        xc = xn;
    }
}

extern "C" void kernel_launch(void* const* d_in, const int* in_sizes, int n_in,
                              void* d_out, int out_size, void* d_ws, size_t ws_size,
                              hipStream_t stream) {
    const float* x       = (const float*)d_in[0];
    const float* conv_w  = (const float*)d_in[1];
    const float* bn_w    = (const float*)d_in[2];
    const float* bn_b    = (const float*)d_in[3];
    const float* bn_mean = (const float*)d_in[4];
    const float* bn_var  = (const float*)d_in[5];
    const float* gamma   = (const float*)d_in[6];
    const float* beta    = (const float*)d_in[7];
    float* out = (float*)d_out;

    float* gap = (float*)d_ws;            // [B*C]           = 32 KiB
    float* A   = gap + Bn * Cn;           // [K][B][C]       = 96 KiB

    gap_kernel<<<Bn * Cn, 256, 0, stream>>>(x, gap);
    filt_kernel<<<(Bn * Kn * Cn) / 256, 256, 0, stream>>>(
        gap, conv_w, bn_w, bn_b, bn_mean, bn_var, gamma, beta, A);
    stencil_kernel<<<(Bn * NSTRIP * HW4n) / 256, 256, 0, stream>>>(x, A, out);
}

// Round 3
// 271.740 us; speedup vs baseline: 1.0142x; 1.0088x over previous
//
#include <hip/hip_runtime.h>
#include <math.h>

// Problem constants (fixed by the reference)
#define Bn   32
#define Cn   256
#define Kn   3
#define HWn  4096      // 64*64
#define HW4n 1024      // HW in float4 units
#define BN_EPS 1e-5f
#define SPC  16        // channels per strip (stencil)
#define NSTRIP (Cn / SPC)

typedef float f4 __attribute__((ext_vector_type(4)));

// ---------------------------------------------------------------------------
// Kernel 1: global average pool. One block per (b,c); 256 threads each read
// 4 float4 (16 floats) -> block reduce -> gap[b*C+c].
// Normal (caching) loads on purpose: this pass warms x into Infinity Cache
// (x = 128 MiB, L3 = 256 MiB -> fully resident) for the stencil pass.
// ---------------------------------------------------------------------------
__global__ __launch_bounds__(256) void gap_kernel(const float* __restrict__ x,
                                                  float* __restrict__ gap) {
    const int bc = blockIdx.x;                     // b*Cn + c
    const f4* px = (const f4*)(x + (size_t)bc * HWn);
    const int t = threadIdx.x;
    float s = 0.f;
#pragma unroll
    for (int i = 0; i < 4; ++i) {
        f4 v = px[t + i * 256];
        s += (v.x + v.y) + (v.z + v.w);
    }
    // wave64 shuffle reduce
#pragma unroll
    for (int off = 32; off > 0; off >>= 1) s += __shfl_down(s, off, 64);
    __shared__ float ls[4];
    const int wave = t >> 6, lane = t & 63;
    if (lane == 0) ls[wave] = s;
    __syncthreads();
    if (t == 0) {
        gap[bc] = (ls[0] + ls[1] + ls[2] + ls[3]) * (1.0f / (float)HWn);
    }
}

// ---------------------------------------------------------------------------
// Kernel 2: f[b,o] = dot(gap[b,:], conv_w[o,:]) -> BN(eval) -> sigmoid,
// then fold gamma/beta into per-(k,b,c) stencil coefficients:
//   a0 = s0*gamma[c]; a1 = s1*gamma[c] + beta[c]; a2 = s2*gamma[c]
// A layout: [K][B][C].
// ---------------------------------------------------------------------------
__global__ __launch_bounds__(256) void filt_kernel(
        const float* __restrict__ gap, const float* __restrict__ conv_w,
        const float* __restrict__ bn_w, const float* __restrict__ bn_b,
        const float* __restrict__ bn_mean, const float* __restrict__ bn_var,
        const float* __restrict__ gamma, const float* __restrict__ beta,
        float* __restrict__ A) {
    const int gid = blockIdx.x * 256 + threadIdx.x;   // 0 .. B*K*C-1
    const int b = gid / (Kn * Cn);
    const int o = gid % (Kn * Cn);
    const f4* g4 = (const f4*)(gap + b * Cn);
    const f4* w4 = (const f4*)(conv_w + (size_t)o * Cn);
    float acc = 0.f;
#pragma unroll 8
    for (int i = 0; i < Cn / 4; ++i) {
        f4 g = g4[i], w = w4[i];
        acc += g.x * w.x + g.y * w.y + g.z * w.z + g.w * w.w;
    }
    float fv = (acc - bn_mean[o]) * rsqrtf(bn_var[o] + BN_EPS) * bn_w[o] + bn_b[o];
    float s = 1.0f / (1.0f + expf(-fv));
    const int k = o / Cn, c = o % Cn;
    float a = (k == 1) ? (s * gamma[c] + beta[c]) : (s * gamma[c]);
    A[(size_t)k * (Bn * Cn) + b * Cn + c] = a;
}

// ---------------------------------------------------------------------------
// Kernel 3: 3-tap channel stencil, rolling register window over SPC=16
// channels per thread. 2048 blocks -> 8 blocks/CU -> 32 waves/CU (max occ).
// x reads: NORMAL loads (x is L3-resident after gap pass; NT loads in R2
// likely bypassed L3 and went to HBM — reverted).
// out writes: NON-TEMPORAL stores (write-once; must not evict x from the
// 256 MiB Infinity Cache mid-pass — x is exactly half of L3).
// Reflect edges: c==0 uses x[1]; c==C-1 uses x[C-2].
// ---------------------------------------------------------------------------
__global__ __launch_bounds__(256) void stencil_kernel(const float* __restrict__ x,
                                                      const float* __restrict__ A,
                                                      float* __restrict__ out) {
    const int gid   = blockIdx.x * 256 + threadIdx.x;
    const int hw4   = gid & (HW4n - 1);
    const int strip = (gid >> 10) & (NSTRIP - 1);
    const int b     = gid >> 14;
    const int c0    = strip * SPC;

    __shared__ float a0s[SPC], a1s[SPC], a2s[SPC];
    const int t = threadIdx.x;
    if (t < 3 * SPC) {
        const int k = t / SPC, cc = t % SPC;
        float v = A[(size_t)k * (Bn * Cn) + b * Cn + c0 + cc];
        if (k == 0) a0s[cc] = v;
        else if (k == 1) a1s[cc] = v;
        else a2s[cc] = v;
    }
    __syncthreads();

    const f4* px  = (const f4*)x;
    f4* pout      = (f4*)out;
    const size_t base = (size_t)b * Cn * HW4n + hw4;   // float4 units

    const int cm = (c0 == 0) ? 1 : c0 - 1;             // reflect at c=0
    f4 xm = px[base + (size_t)cm * HW4n];
    f4 xc = px[base + (size_t)c0 * HW4n];

#pragma unroll 4
    for (int i = 0; i < SPC; ++i) {
        const int c  = c0 + i;
        const int cn = (c == Cn - 1) ? (Cn - 2) : (c + 1);   // reflect at c=C-1
        f4 xn = px[base + (size_t)cn * HW4n];
        const float a0 = a0s[i], a1 = a1s[i], a2 = a2s[i];
        f4 o;
        o.x = fmaf(a0, xm.x, fmaf(a1, xc.x, a2 * xn.x));
        o.y = fmaf(a0, xm.y, fmaf(a1, xc.y, a2 * xn.y));
        o.z = fmaf(a0, xm.z, fmaf(a1, xc.z, a2 * xn.z));
        o.w = fmaf(a0, xm.w, fmaf(a1, xc.w, a2 * xn.w));
        __builtin_nontemporal_store(o, &pout[base + (size_t)c * HW4n]);
        xm = xc;
        xc = xn;
    }
}

extern "C" void kernel_launch(void* const* d_in, const int* in_sizes, int n_in,
                              void* d_out, int out_size, void* d_ws, size_t ws_size,
                              hipStream_t stream) {
    const float* x       = (const float*)d_in[0];
    const float* conv_w  = (const float*)d_in[1];
    const float* bn_w    = (const float*)d_in[2];
    const float* bn_b    = (const float*)d_in[3];
    const float* bn_mean = (const float*)d_in[4];
    const float* bn_var  = (const float*)d_in[5];
    const float* gamma   = (const float*)d_in[6];
    const float* beta    = (const float*)d_in[7];
    float* out = (float*)d_out;

    float* gap = (float*)d_ws;            // [B*C]           = 32 KiB
    float* A   = gap + Bn * Cn;           // [K][B][C]       = 96 KiB

    gap_kernel<<<Bn * Cn, 256, 0, stream>>>(x, gap);
    filt_kernel<<<(Bn * Kn * Cn) / 256, 256, 0, stream>>>(
        gap, conv_w, bn_w, bn_b, bn_mean, bn_var, gamma, beta, A);
    stencil_kernel<<<(Bn * NSTRIP * HW4n) / 256, 256, 0, stream>>>(x, A, out);
}